// Round 1
// baseline (1052.687 us; speedup 1.0000x reference)
//
#include <hip/hip_runtime.h>

#define NROWS 16384
#define KCODES 8192
#define DDIM 256
#define BM 128
#define BN 128
#define BD 8
#define KCHUNKS 4
#define TILES_PER_CHUNK ((KCODES / KCHUNKS) / BN)  // 16

// ---------------- init: best keys to +inf, loss accumulator to 0 ----------------
__global__ void k_init(unsigned long long* best, float* accum) {
    int i = blockIdx.x * blockDim.x + threadIdx.x;
    if (i < NROWS) best[i] = 0xFFFFFFFFFFFFFFFFull;
    if (i == 0) accum[0] = 0.0f;
}

// ---------------- row sum-of-squares: one wave per row, 4 rows/block ----------------
__global__ void k_sumsq(const float* __restrict__ in, float* __restrict__ out, int rows) {
    int row = blockIdx.x * 4 + (threadIdx.x >> 6);
    int lane = threadIdx.x & 63;
    if (row >= rows) return;
    const float4 v = *reinterpret_cast<const float4*>(in + row * DDIM + lane * 4);
    float s = v.x * v.x + v.y * v.y + v.z * v.z + v.w * v.w;
    #pragma unroll
    for (int off = 32; off > 0; off >>= 1) s += __shfl_down(s, off);
    if (lane == 0) out[row] = s;
}

// ---------------- main: fused dist GEMM + argmin ----------------
// dist(n,k) = (z2[n] + e2[k]) - 2*dot(z[n], cb[k]); argmin over k, ties -> lowest k.
__global__ __launch_bounds__(256) void k_argmin(
    const float* __restrict__ z, const float* __restrict__ cb,
    const float* __restrict__ z2, const float* __restrict__ e2,
    unsigned long long* __restrict__ best)
{
    // smem: staging [8][128] z + [8][128] c (8 KB), overlaid with u64 red[128][17] (17408 B)
    __shared__ __align__(16) char smem_raw[17408];
    float* zs = (float*)smem_raw;
    float* cs = (float*)(smem_raw + 4096);
    unsigned long long* red = (unsigned long long*)smem_raw;

    const int tid = threadIdx.x;
    const int tr = tid & 15;
    const int tc = tid >> 4;
    const int rt = blockIdx.x & 127;   // row tile
    const int kc = blockIdx.x >> 7;    // k chunk
    const int row0 = rt * BM;
    const int rl = tid >> 1;           // staging row 0..127
    const int dl = (tid & 1) * 4;      // staging d offset {0,4}

    int rows[8];
    #pragma unroll
    for (int i = 0; i < 4; ++i) { rows[i] = tr * 4 + i; rows[i + 4] = 64 + tr * 4 + i; }

    float z2r[8];
    #pragma unroll
    for (int i = 0; i < 8; ++i) z2r[i] = z2[row0 + rows[i]];

    unsigned long long bestk[8];
    #pragma unroll
    for (int i = 0; i < 8; ++i) bestk[i] = 0xFFFFFFFFFFFFFFFFull;

    for (int t = 0; t < TILES_PER_CHUNK; ++t) {
        const int c0 = kc * (KCODES / KCHUNKS) + t * BN;
        float acc[8][8];
        #pragma unroll
        for (int i = 0; i < 8; ++i)
            #pragma unroll
            for (int j = 0; j < 8; ++j) acc[i][j] = 0.0f;

        for (int dc = 0; dc < DDIM; dc += BD) {
            // issue global loads before the barrier (latency overlap)
            const float4 va = *reinterpret_cast<const float4*>(z  + (row0 + rl) * DDIM + dc + dl);
            const float4 vb = *reinterpret_cast<const float4*>(cb + (c0   + rl) * DDIM + dc + dl);
            __syncthreads();  // previous iteration's readers done
            zs[(dl + 0) * BM + rl] = va.x; zs[(dl + 1) * BM + rl] = va.y;
            zs[(dl + 2) * BM + rl] = va.z; zs[(dl + 3) * BM + rl] = va.w;
            cs[(dl + 0) * BN + rl] = vb.x; cs[(dl + 1) * BN + rl] = vb.y;
            cs[(dl + 2) * BN + rl] = vb.z; cs[(dl + 3) * BN + rl] = vb.w;
            __syncthreads();
            #pragma unroll
            for (int d = 0; d < BD; ++d) {
                const float4 a0 = *reinterpret_cast<const float4*>(zs + d * BM + tr * 4);
                const float4 a1 = *reinterpret_cast<const float4*>(zs + d * BM + 64 + tr * 4);
                const float4 b0 = *reinterpret_cast<const float4*>(cs + d * BN + tc * 4);
                const float4 b1 = *reinterpret_cast<const float4*>(cs + d * BN + 64 + tc * 4);
                const float a[8] = {a0.x, a0.y, a0.z, a0.w, a1.x, a1.y, a1.z, a1.w};
                const float b[8] = {b0.x, b0.y, b0.z, b0.w, b1.x, b1.y, b1.z, b1.w};
                #pragma unroll
                for (int i = 0; i < 8; ++i)
                    #pragma unroll
                    for (int j = 0; j < 8; ++j)
                        acc[i][j] = fmaf(a[i], b[j], acc[i][j]);
            }
        }
        // epilogue: dist + running argmin (register-only)
        int cols[8];
        #pragma unroll
        for (int j = 0; j < 4; ++j) { cols[j] = tc * 4 + j; cols[j + 4] = 64 + tc * 4 + j; }
        float e2r[8];
        #pragma unroll
        for (int j = 0; j < 8; ++j) e2r[j] = e2[c0 + cols[j]];
        #pragma unroll
        for (int i = 0; i < 8; ++i) {
            #pragma unroll
            for (int j = 0; j < 8; ++j) {
                const float s = z2r[i] + e2r[j];
                const float dist = s - 2.0f * acc[i][j];
                const unsigned long long key =
                    ((unsigned long long)__float_as_uint(dist) << 32) |
                    (unsigned)(c0 + cols[j]);
                if (key < bestk[i]) bestk[i] = key;
            }
        }
    }

    // block reduce over the 16 tc-threads per row, then one global atomic per row
    __syncthreads();
    #pragma unroll
    for (int i = 0; i < 8; ++i) red[rows[i] * 17 + tc] = bestk[i];
    __syncthreads();
    if (tid < BM) {
        unsigned long long m = red[tid * 17 + 0];
        #pragma unroll
        for (int t2 = 1; t2 < 16; ++t2) {
            const unsigned long long v = red[tid * 17 + t2];
            if (v < m) m = v;
        }
        atomicMin(&best[row0 + tid], m);
    }
}

// ---------------- gather + z_st + loss partial sums ----------------
__global__ void k_gather(const float* __restrict__ z, const float* __restrict__ cb,
                         const unsigned long long* __restrict__ best,
                         float* __restrict__ out, float* __restrict__ accum)
{
    __shared__ float wsum[4];
    const int row = blockIdx.x;
    const int d = threadIdx.x;
    const unsigned k = (unsigned)(best[row] & 0xFFFFFFFFull);
    const float ze = z[row * DDIM + d];
    const float cq = cb[k * DDIM + d];
    const float zst = ze + (cq - ze);   // straight-through, ref rounding order
    out[row * DDIM + d] = zst;
    const float df = cq - ze;
    float s = df * df;
    #pragma unroll
    for (int off = 32; off > 0; off >>= 1) s += __shfl_down(s, off);
    const int wid = d >> 6;
    if ((d & 63) == 0) wsum[wid] = s;
    __syncthreads();
    if (d == 0) {
        const float tot = wsum[0] + wsum[1] + wsum[2] + wsum[3];
        atomicAdd(accum, tot);
        out[NROWS * DDIM + row] = (float)k;   // idx as float
    }
}

// ---------------- final scalars ----------------
__global__ void k_final(const float* __restrict__ accum, float* __restrict__ out) {
    const float m = accum[0] / (float)(NROWS * DDIM);
    out[NROWS * DDIM + NROWS + 0] = m;  // commit
    out[NROWS * DDIM + NROWS + 1] = m;  // codebook_loss (identical value)
}

extern "C" void kernel_launch(void* const* d_in, const int* in_sizes, int n_in,
                              void* d_out, int out_size, void* d_ws, size_t ws_size,
                              hipStream_t stream)
{
    const float* z  = (const float*)d_in[0];   // z_e (16,32,32,256) fp32
    const float* cb = (const float*)d_in[1];   // codebook (8192,256) fp32
    float* out = (float*)d_out;

    char* ws = (char*)d_ws;
    unsigned long long* best = (unsigned long long*)ws;                 // 16384 * 8 B
    float* e2    = (float*)(ws + NROWS * 8);                            // 8192 * 4 B
    float* z2    = (float*)(ws + NROWS * 8 + KCODES * 4);               // 16384 * 4 B
    float* accum = (float*)(ws + NROWS * 8 + KCODES * 4 + NROWS * 4);   // 1 * 4 B

    k_init<<<(NROWS + 255) / 256, 256, 0, stream>>>(best, accum);
    k_sumsq<<<KCODES / 4, 256, 0, stream>>>(cb, e2, KCODES);
    k_sumsq<<<NROWS / 4, 256, 0, stream>>>(z, z2, NROWS);
    k_argmin<<<128 * KCHUNKS, 256, 0, stream>>>(z, cb, z2, e2, best);
    k_gather<<<NROWS, 256, 0, stream>>>(z, cb, best, out, accum);
    k_final<<<1, 1, 0, stream>>>(accum, out);
}